// Round 11
// baseline (306.651 us; speedup 1.0000x reference)
//
#include <hip/hip_runtime.h>

#define NODE_NUM 2000
#define DM 2048          // D_MODEL, also padded K/N
#define IN_DIM 7
#define CONV_CH 64
#define KER 49
#define BATCH 64

typedef __attribute__((ext_vector_type(8))) short bf16x8;
typedef __attribute__((ext_vector_type(4))) float f32x4;
typedef __attribute__((ext_vector_type(4))) unsigned int u32x4;

__device__ __forceinline__ float bf2f(unsigned short u) {
  union { unsigned int i; float f; } c; c.i = ((unsigned int)u) << 16; return c.f;
}
__device__ __forceinline__ unsigned short f2bf(float f) {
  union { float f; unsigned int i; } c; c.f = f;
  unsigned int r = c.i + 0x7FFFu + ((c.i >> 16) & 1u);
  return (unsigned short)(r >> 16);
}

// ---------------------------------------------------------------------------
// Adjacency (round-9 verified): 4 rows/block, 8 consecutive w per thread.
// ---------------------------------------------------------------------------
__global__ __launch_bounds__(256) void adj_kernel(const float* __restrict__ nv1,
                                                  const float* __restrict__ nv2,
                                                  unsigned short* __restrict__ Ab) {
  const int bid = blockIdx.x;
  const int tid = threadIdx.x;
  if (bid >= 500) {
    const int r0 = 2000 + (bid - 500) * 4;
    for (int i = tid; i < 4 * 2048; i += 256)
      Ab[(size_t)(r0 + (i >> 11)) * DM + (i & 2047)] = 0;
    return;
  }
  const int v0 = bid * 4;
  __shared__ float e1s[4][40];
  __shared__ float redm[4][4], redsum[4][4];
  for (int i = tid; i < 160; i += 256) e1s[i / 40][i % 40] = nv1[(v0 + i / 40) * 40 + i % 40];
  __syncthreads();
  const int w0 = tid * 8;
  const bool oob = (w0 >= NODE_NUM);
  const float* base = nv2 + (oob ? 0 : w0);
  float acc[4][8] = {};
  f32x4 xa = *(const f32x4*)(base);
  f32x4 xb = *(const f32x4*)(base + 4);
  for (int k = 0; k < 40; ++k) {
    const f32x4 ca = xa, cb = xb;
    if (k < 39) {
      xa = *(const f32x4*)(base + (k + 1) * NODE_NUM);
      xb = *(const f32x4*)(base + (k + 1) * NODE_NUM + 4);
    }
#pragma unroll
    for (int v = 0; v < 4; ++v) {
      const float e = e1s[v][k];
#pragma unroll
      for (int i = 0; i < 4; ++i) {
        acc[v][i]     = fmaf(e, ca[i], acc[v][i]);
        acc[v][i + 4] = fmaf(e, cb[i], acc[v][i + 4]);
      }
    }
  }
  const int wid = tid >> 6, lane = tid & 63;
#pragma unroll
  for (int v = 0; v < 4; ++v) {
    float mx = -1e30f;
    if (!oob) {
#pragma unroll
      for (int i = 0; i < 8; ++i) {
        acc[v][i] = fmaxf(acc[v][i], 0.f);
        mx = fmaxf(mx, acc[v][i]);
      }
    }
    for (int o = 32; o; o >>= 1) mx = fmaxf(mx, __shfl_xor(mx, o));
    if (lane == 0) redm[v][wid] = mx;
  }
  __syncthreads();
#pragma unroll
  for (int v = 0; v < 4; ++v) {
    const float mx = fmaxf(fmaxf(redm[v][0], redm[v][1]), fmaxf(redm[v][2], redm[v][3]));
    float sum = 0.f;
    if (!oob) {
#pragma unroll
      for (int i = 0; i < 8; ++i) { const float e = __expf(acc[v][i] - mx); acc[v][i] = e; sum += e; }
    }
    for (int o = 32; o; o >>= 1) sum += __shfl_xor(sum, o);
    if (lane == 0) redsum[v][wid] = sum;
  }
  __syncthreads();
#pragma unroll
  for (int v = 0; v < 4; ++v) {
    const float sum = redsum[v][0] + redsum[v][1] + redsum[v][2] + redsum[v][3];
    const float inv = 0.5f / sum;
    const int vg = v0 + v;
    unsigned short out[8];
#pragma unroll
    for (int i = 0; i < 8; ++i) {
      const float val = oob ? 0.f : (acc[v][i] * inv + ((w0 + i == vg) ? 0.5f : 0.f));
      out[i] = f2bf(val);
    }
    *(u32x4*)(Ab + (size_t)vg * DM + w0) = *(const u32x4*)out;
  }
}

// ---------------------------------------------------------------------------
// Pack conv weights into per-lane MFMA A-fragment order (bf16).
// ---------------------------------------------------------------------------
__global__ __launch_bounds__(256) void wpack_kernel(const float* __restrict__ wst,
                                                    unsigned short* __restrict__ wpack) {
  const int idx = blockIdx.x * 256 + threadIdx.x;   // 112 blocks
  const int e = idx & 7;
  const int lane = (idx >> 3) & 63;
  const int w = (idx >> 9) & 3;
  const int kstep = idx >> 11;
  const int c = w * 16 + (lane & 15);
  const int k = kstep * 32 + (lane >> 4) * 8 + e;
  const int ci = k >> 6, kern = k & 63;
  const float val = (kern < KER) ? wst[(c * IN_DIM + ci) * KER + kern] : 0.f;
  wpack[idx] = f2bf(val);
}

// ---------------------------------------------------------------------------
// Pack MLP weights to bf16 once.
// ---------------------------------------------------------------------------
__global__ __launch_bounds__(256) void wmpack_kernel(const float* __restrict__ wm,
                                                     unsigned short* __restrict__ wmb) {
  const int idx = blockIdx.x * 256 + threadIdx.x;   // 64 blocks = 16384
  wmb[idx] = f2bf(wm[idx]);
}

// ---------------------------------------------------------------------------
// Start conv via MFMA with shift-replicated x copies (round-7 verified).
// ---------------------------------------------------------------------------
__global__ __launch_bounds__(256) void conv_kernel(const float* __restrict__ x,
                                                   const unsigned short* __restrict__ wpack,
                                                   const float* __restrict__ bst,
                                                   unsigned short* __restrict__ H0) {
  __shared__ alignas(16) unsigned short xcopy[8 * 7 * 128];  // 14336 B
  const int b = blockIdx.y;
  const int n0 = blockIdx.x * 64;
  const int tid = threadIdx.x;
  const int wv = tid >> 6, lane = tid & 63;
  const int l15 = lane & 15, kg = lane >> 4;
  bf16x8 af[14];
#pragma unroll
  for (int ks = 0; ks < 14; ++ks)
    af[ks] = *(const bf16x8*)(wpack + ((size_t)(ks * 4 + wv) * 64 + lane) * 8);
  f32x4 acc[4];
  {
    const f32x4 bv = *(const f32x4*)(bst + wv * 16 + kg * 4);
#pragma unroll
    for (int nf = 0; nf < 4; ++nf) acc[nf] = bv;
  }
  const size_t xb = (size_t)b * (IN_DIM * DM);
#pragma unroll
  for (int it = 0; it < 14; ++it) {
    const int row = it * 4 + (tid >> 6);       // 0..55
    const int s = row / 7, ci = row % 7;
    const int j = (tid & 63) * 2;
    int g0 = n0 + j + s;     if (g0 > DM - 1) g0 = DM - 1;
    int g1 = n0 + j + 1 + s; if (g1 > DM - 1) g1 = DM - 1;
    const float v0 = x[xb + ci * DM + g0];
    const float v1 = x[xb + ci * DM + g1];
    const unsigned int pk = (unsigned int)f2bf(v0) | ((unsigned int)f2bf(v1) << 16);
    *(unsigned int*)((char*)xcopy + row * 256 + j * 2) = pk;
  }
  __syncthreads();
#pragma unroll
  for (int ks = 0; ks < 14; ++ks) {
    const int ci = ks >> 1;
    const int kern0 = ((ks & 1) << 5) + kg * 8;
#pragma unroll
    for (int nf = 0; nf < 4; ++nf) {
      const int q = nf * 16 + l15 + kern0;
      const int byte = ((q & 7) * 7 + ci) * 256 + (q & ~7) * 2;
      const bf16x8 bfr = *(const bf16x8*)((const char*)xcopy + byte);
      acc[nf] = __builtin_amdgcn_mfma_f32_16x16x32_bf16(af[ks], bfr, acc[nf], 0, 0, 0);
    }
  }
#pragma unroll
  for (int nf = 0; nf < 4; ++nf) {
#pragma unroll
    for (int r = 0; r < 4; ++r) {
      const int c = wv * 16 + kg * 4 + r;
      const int n = n0 + nf * 16 + l15;
      H0[(size_t)(b * 64 + c) * DM + n] =
          (n < NODE_NUM) ? f2bf(acc[nf][r]) : (unsigned short)0;
    }
  }
}

// ---------------------------------------------------------------------------
// Mixprop NT-GEMM, 256x128 tile, 8 waves, phase-interleaved (8-phase style):
// per K-step: vmcnt(0)+barrier (loads a full iter old), then 4 phases of
// {ds_read frags || stage-issue next tile -> other buffer, lgkmcnt(0),
//  setprio(1), 8 MFMA, setprio(0)}. One barrier per K-step.
// out = bf16(0.05*H0 + 0.95*acc). T1 bijective XCD swizzle (nwg=256).
// ---------------------------------------------------------------------------
__global__ __launch_bounds__(512) void gemm256(const unsigned short* __restrict__ A,
                                               const unsigned short* __restrict__ Bt,
                                               const unsigned short* __restrict__ H0,
                                               unsigned short* __restrict__ C) {
  __shared__ alignas(16) unsigned short As[2][256 * 64];   // 2 x 32 KB
  __shared__ alignas(16) unsigned short Bs[2][128 * 64];   // 2 x 16 KB
  const int tid = threadIdx.x;
  const int lin = blockIdx.y * 16 + blockIdx.x;
  const int swz = (lin & 7) * 32 + (lin >> 3);             // bijective, nwg=256
  const int bx = swz & 15, by = swz >> 4;
  const int n0 = bx * 128, m0 = by * 256;
  const int wid = tid >> 6, lane = tid & 63;
  const int wr = wid >> 2, wc = wid & 3;                   // 2M x 4N waves
  const int l15 = lane & 15, kg = lane >> 4;

  auto stageA = [&](int buf, int k0, int it) {
    const int linb = it * 8192 + tid * 16;
    const int row = linb >> 7;
    const int blog = (linb & 127) ^ ((row & 7) << 4);
    const char* s = (const char*)A + ((size_t)(m0 + row) * DM + k0) * 2 + blog;
    __builtin_amdgcn_global_load_lds((const __attribute__((address_space(1))) void*)s,
        (__attribute__((address_space(3))) void*)((char*)As[buf] + linb), 16, 0, 0);
  };
  auto stageB = [&](int buf, int k0, int it) {
    const int linb = it * 8192 + tid * 16;
    const int row = linb >> 7;
    const int blog = (linb & 127) ^ ((row & 7) << 4);
    const char* s = (const char*)Bt + ((size_t)(n0 + row) * DM + k0) * 2 + blog;
    __builtin_amdgcn_global_load_lds((const __attribute__((address_space(1))) void*)s,
        (__attribute__((address_space(3))) void*)((char*)Bs[buf] + linb), 16, 0, 0);
  };

  f32x4 acc[8][2] = {};
  // prologue: tile 0 -> buf 0
  stageA(0, 0, 0); stageA(0, 0, 1); stageA(0, 0, 2); stageA(0, 0, 3);
  stageB(0, 0, 0); stageB(0, 0, 1);

  for (int t = 0; t < 32; ++t) {
    const int cur = t & 1, nxt = cur ^ 1;
    const int kn = (t + 1) * 64;
    const bool pf = (t + 1 < 32);
    asm volatile("s_waitcnt vmcnt(0)" ::: "memory");   // tile t resident (issued iter t-1)
    __builtin_amdgcn_s_barrier();                      // everyone done reading buf nxt
    __builtin_amdgcn_sched_barrier(0);
    bf16x8 bfrag[2][2];
#pragma unroll
    for (int p = 0; p < 4; ++p) {
      // A-frags for this phase's two mf rows
      bf16x8 afr[2][2];
#pragma unroll
      for (int ml = 0; ml < 2; ++ml) {
        const int ra = wr * 128 + (p * 2 + ml) * 16 + l15;
        const int rowoff = ra * 128;
        const int sw = (ra & 7) << 4;
#pragma unroll
        for (int kk = 0; kk < 2; ++kk)
          afr[kk][ml] = *(const bf16x8*)((const char*)As[cur] + rowoff + ((kk * 64 + kg * 16) ^ sw));
      }
      if (p == 0) {
#pragma unroll
        for (int nf = 0; nf < 2; ++nf) {
          const int rb = wc * 32 + nf * 16 + l15;
          const int rowoff = rb * 128;
          const int sw = (rb & 7) << 4;
#pragma unroll
          for (int kk = 0; kk < 2; ++kk)
            bfrag[kk][nf] = *(const bf16x8*)((const char*)Bs[cur] + rowoff + ((kk * 64 + kg * 16) ^ sw));
        }
      }
      // stage next tile into the other buffer (issue-early)
      if (pf) {
        if (p == 0) { stageA(nxt, kn, 0); stageA(nxt, kn, 1); }
        else if (p == 1) { stageA(nxt, kn, 2); stageA(nxt, kn, 3); }
        else if (p == 2) { stageB(nxt, kn, 0); stageB(nxt, kn, 1); }
      }
      asm volatile("s_waitcnt lgkmcnt(0)" ::: "memory");
      __builtin_amdgcn_sched_barrier(0);
      __builtin_amdgcn_s_setprio(1);
#pragma unroll
      for (int kk = 0; kk < 2; ++kk)
#pragma unroll
        for (int ml = 0; ml < 2; ++ml)
#pragma unroll
          for (int nf = 0; nf < 2; ++nf)
            acc[p * 2 + ml][nf] = __builtin_amdgcn_mfma_f32_16x16x32_bf16(
                afr[kk][ml], bfrag[kk][nf], acc[p * 2 + ml][nf], 0, 0, 0);
      __builtin_amdgcn_s_setprio(0);
    }
  }
  const int l4 = lane >> 4;
#pragma unroll
  for (int mf = 0; mf < 8; ++mf) {
#pragma unroll
    for (int nf = 0; nf < 2; ++nf) {
#pragma unroll
      for (int r = 0; r < 4; ++r) {
        const int gm = m0 + wr * 128 + mf * 16 + l4 * 4 + r;
        const int gn = n0 + wc * 32 + nf * 16 + l15;
        const float v = 0.05f * bf2f(H0[(size_t)gm * DM + gn]) + 0.95f * acc[mf][nf][r];
        C[(size_t)gm * DM + gn] = f2bf(v);
      }
    }
  }
}

// ---------------------------------------------------------------------------
// Split-K final GEMM (round-6 verified depth-2 structure), MODE 1 only.
// ---------------------------------------------------------------------------
__global__ __launch_bounds__(256) void gemm_tail(const unsigned short* __restrict__ A,
                                                 const unsigned short* __restrict__ Bt,
                                                 float* __restrict__ Cout) {
  __shared__ alignas(16) unsigned short As[2][128 * 64];
  __shared__ alignas(16) unsigned short Bs[2][128 * 64];
  const int tid = threadIdx.x;
  const int bx = blockIdx.x, by = blockIdx.y;
  const int n0 = bx * 128;
  const int m0 = 0;
  const int kbeg = by * 256;
  const int nt = 4;
  const int wid = tid >> 6, lane = tid & 63;
  const int wr = wid >> 1, wc = wid & 1;
  const int l15 = lane & 15, kg = lane >> 4;

  auto STAGE = [&](int buf, int k0) {
#pragma unroll
    for (int it = 0; it < 4; ++it) {
      const int lin = it * 4096 + tid * 16;
      const int row = lin >> 7;
      const int blog = (lin & 127) ^ ((row & 7) << 4);
      const char* sa = (const char*)A + ((size_t)(m0 + row) * DM + k0) * 2 + blog;
      const char* sb = (const char*)Bt + ((size_t)(n0 + row) * DM + k0) * 2 + blog;
      __builtin_amdgcn_global_load_lds((const __attribute__((address_space(1))) void*)sa,
                                       (__attribute__((address_space(3))) void*)((char*)As[buf] + lin),
                                       16, 0, 0);
      __builtin_amdgcn_global_load_lds((const __attribute__((address_space(1))) void*)sb,
                                       (__attribute__((address_space(3))) void*)((char*)Bs[buf] + lin),
                                       16, 0, 0);
    }
  };

  f32x4 acc[4][4] = {};
  STAGE(0, kbeg);
  STAGE(1, kbeg + 64);

  for (int t = 0; t < nt; ++t) {
    const int cur = t & 1;
    if (t + 1 < nt) asm volatile("s_waitcnt vmcnt(8)" ::: "memory");
    else            asm volatile("s_waitcnt vmcnt(0)" ::: "memory");
    __builtin_amdgcn_s_barrier();
    __builtin_amdgcn_sched_barrier(0);
    bf16x8 af[2][4], bfr[2][4];
#pragma unroll
    for (int f = 0; f < 4; ++f) {
      const int ra = wr * 64 + f * 16 + l15;
      const int rb = wc * 64 + f * 16 + l15;
#pragma unroll
      for (int kk = 0; kk < 2; ++kk) {
        const int off = kk * 64 + kg * 16;
        af[kk][f]  = *(const bf16x8*)((const char*)As[cur] + ra * 128 + (off ^ ((ra & 7) << 4)));
        bfr[kk][f] = *(const bf16x8*)((const char*)Bs[cur] + rb * 128 + (off ^ ((rb & 7) << 4)));
      }
    }
    asm volatile("s_waitcnt lgkmcnt(0)" ::: "memory");
    __builtin_amdgcn_sched_barrier(0);
    __builtin_amdgcn_s_barrier();
    __builtin_amdgcn_sched_barrier(0);
    if (t + 2 < nt) STAGE(cur, kbeg + (t + 2) * 64);
#pragma unroll
    for (int kk = 0; kk < 2; ++kk)
#pragma unroll
      for (int mf = 0; mf < 4; ++mf)
#pragma unroll
        for (int nf = 0; nf < 4; ++nf)
          acc[mf][nf] = __builtin_amdgcn_mfma_f32_16x16x32_bf16(af[kk][mf], bfr[kk][nf],
                                                                acc[mf][nf], 0, 0, 0);
  }
  const int l4 = lane >> 4;
#pragma unroll
  for (int mf = 0; mf < 4; ++mf) {
#pragma unroll
    for (int nf = 0; nf < 4; ++nf) {
#pragma unroll
      for (int r = 0; r < 4; ++r) {
        const int gm = m0 + wr * 64 + mf * 16 + l4 * 4 + r;
        const int gn = n0 + wc * 64 + nf * 16 + l15;
        if (gm < 64)
          Cout[(size_t)by * 64 * DM + (size_t)gm * DM + gn] = acc[mf][nf][r];
      }
    }
  }
}

// ---------------------------------------------------------------------------
// MLP via MFMA (verified structure, pre-packed bf16 weights).
// ---------------------------------------------------------------------------
__global__ __launch_bounds__(256) void mlp_kernel(const unsigned short* __restrict__ h0,
                                                  const unsigned short* __restrict__ h1,
                                                  const unsigned short* __restrict__ h2,
                                                  const unsigned short* __restrict__ h3,
                                                  const unsigned short* __restrict__ wmb,
                                                  const float* __restrict__ bm,
                                                  const float* __restrict__ we,
                                                  const float* __restrict__ be,
                                                  unsigned short* __restrict__ out1) {
  __shared__ alignas(16) unsigned short hs[64 * 264];
  __shared__ alignas(16) unsigned short wl[64 * 264];
  __shared__ float cbuf[128];
  const int b = blockIdx.y;
  const int gn0 = blockIdx.x * 64;
  const int tid = threadIdx.x;
#pragma unroll
  for (int it = 0; it < 8; ++it) {
    const int idx = it * 256 + tid;
    const int o = idx >> 5, c = (idx & 31) * 8;
    *(bf16x8*)&wl[o * 264 + c] = *(const bf16x8*)(wmb + o * 256 + c);
  }
  if (tid < 64) cbuf[tid] = bm[tid];
  else if (tid < 128) cbuf[tid] = we[tid - 64];
  char* hsb = (char*)hs;
#pragma unroll
  for (int it = 0; it < 8; ++it) {
    const int idx = it * 256 + tid;
    const int cf = idx >> 3, n0 = (idx & 7) * 8;
    const int hop = cf >> 6, c = cf & 63;
    const unsigned short* hb = (hop == 0) ? h0 : (hop == 1) ? h1 : (hop == 2) ? h2 : h3;
    const unsigned long long* p =
        (const unsigned long long*)(hb + (size_t)(b * 64 + c) * DM + gn0 + n0);
    const unsigned long long lo = p[0], hi = p[1];
#pragma unroll
    for (int t = 0; t < 8; ++t) {
      const int i = (t + tid) & 7;
      const unsigned short val = (unsigned short)(((i & 4) ? hi : lo) >> ((i & 3) * 16));
      *(unsigned short*)(hsb + (n0 + i) * 528 + cf * 2) = val;
    }
  }
  __syncthreads();
  const int wid = tid >> 6, lane = tid & 63;
  const int l15 = lane & 15, kg = lane >> 4;
  const char* wb = (const char*)wl;
  f32x4 acc[4] = {};
#pragma unroll
  for (int kk = 0; kk < 8; ++kk) {
    const int koff = kk * 64 + kg * 16;
    const bf16x8 bfr = *(const bf16x8*)(hsb + (wid * 16 + l15) * 528 + koff);
#pragma unroll
    for (int mf = 0; mf < 4; ++mf) {
      const bf16x8 af = *(const bf16x8*)(wb + (mf * 16 + l15) * 528 + koff);
      acc[mf] = __builtin_amdgcn_mfma_f32_16x16x32_bf16(af, bfr, acc[mf], 0, 0, 0);
    }
  }
  float pl = 0.f;
#pragma unroll
  for (int mf = 0; mf < 4; ++mf) {
#pragma unroll
    for (int r = 0; r < 4; ++r) {
      const int o = mf * 16 + kg * 4 + r;
      const float s = acc[mf][r] + cbuf[o];
      const float g = 0.5f * s * (1.f + erff(s * 0.70710678118f));
      pl += cbuf[64 + o] * g;
    }
  }
  pl += __shfl_xor(pl, 16);
  pl += __shfl_xor(pl, 32);
  if (kg == 0) {
    const int n = gn0 + wid * 16 + l15;
    out1[(size_t)b * DM + n] = (n < NODE_NUM) ? f2bf(pl + be[0]) : (unsigned short)0;
  }
}

// ---------------------------------------------------------------------------
// w_lin (2048 x 2000 f32) -> bf16 [2048][2048], pad cols zeroed (vectorized)
// ---------------------------------------------------------------------------
__global__ __launch_bounds__(256) void wlin_cvt(const float* __restrict__ wlin,
                                                unsigned short* __restrict__ wl) {
  const int idx = (blockIdx.x * 256 + threadIdx.x) * 8;   // 2048 blocks
  const int d = idx >> 11, w0 = idx & 2047;
  unsigned short out[8];
#pragma unroll
  for (int j = 0; j < 8; ++j) {
    const int w = w0 + j;
    out[j] = (w < NODE_NUM) ? f2bf(wlin[d * NODE_NUM + w]) : (unsigned short)0;
  }
  *(u32x4*)(wl + idx) = *(const u32x4*)out;
}

// ---------------------------------------------------------------------------
// sum 8 split-K partials, +b_lin, LayerNorm over 2048, f32 out
// ---------------------------------------------------------------------------
__global__ __launch_bounds__(256) void ln_kernel(const float* __restrict__ yp,
                                                 const float* __restrict__ bl,
                                                 const float* __restrict__ g,
                                                 const float* __restrict__ bb,
                                                 float* __restrict__ out) {
  const int b = blockIdx.x, tid = threadIdx.x;
  __shared__ float rs[4], rq[4];
  float v[8];
  float s = 0.f;
#pragma unroll
  for (int i = 0; i < 8; ++i) {
    const int d = i * 256 + tid;
    float acc = bl[d];
#pragma unroll
    for (int sp = 0; sp < 8; ++sp) acc += yp[(size_t)sp * 64 * DM + (size_t)b * DM + d];
    v[i] = acc;
    s += acc;
  }
  for (int o = 32; o; o >>= 1) s += __shfl_xor(s, o);
  const int wid = tid >> 6, lane = tid & 63;
  if (lane == 0) rs[wid] = s;
  __syncthreads();
  s = rs[0] + rs[1] + rs[2] + rs[3];
  const float mu = s * (1.f / 2048.f);
  float q = 0.f;
#pragma unroll
  for (int i = 0; i < 8; ++i) { const float d = v[i] - mu; q += d * d; }
  for (int o = 32; o; o >>= 1) q += __shfl_xor(q, o);
  if (lane == 0) rq[wid] = q;
  __syncthreads();
  q = rq[0] + rq[1] + rq[2] + rq[3];
  const float inv = rsqrtf(q * (1.f / 2048.f) + 1e-5f);
#pragma unroll
  for (int i = 0; i < 8; ++i) {
    const int d = i * 256 + tid;
    out[(size_t)b * DM + d] = (v[i] - mu) * inv * g[d] + bb[d];
  }
}

// ---------------------------------------------------------------------------
extern "C" void kernel_launch(void* const* d_in, const int* in_sizes, int n_in,
                              void* d_out, int out_size, void* d_ws, size_t ws_size,
                              hipStream_t stream) {
  const float* x      = (const float*)d_in[0];
  const float* nv1    = (const float*)d_in[1];
  const float* nv2    = (const float*)d_in[2];
  const float* w_st   = (const float*)d_in[3];
  const float* b_st   = (const float*)d_in[4];
  const float* w_mlp  = (const float*)d_in[5];
  const float* b_mlp  = (const float*)d_in[6];
  const float* w_end  = (const float*)d_in[7];
  const float* b_end  = (const float*)d_in[8];
  const float* w_lin  = (const float*)d_in[9];
  const float* b_lin  = (const float*)d_in[10];
  const float* ln_g   = (const float*)d_in[11];
  const float* ln_b   = (const float*)d_in[12];

  char* ws = (char*)d_ws;
  const size_t SZ_A = (size_t)DM * DM * 2;    // 8 MB
  const size_t SZ_H = (size_t)4096 * DM * 2;  // 16 MB
  unsigned short* Ab    = (unsigned short*)(ws);
  unsigned short* H0    = (unsigned short*)(ws + SZ_A);
  unsigned short* H1    = (unsigned short*)(ws + SZ_A + SZ_H);
  unsigned short* H2    = (unsigned short*)(ws + SZ_A + 2 * SZ_H);
  unsigned short* H3    = (unsigned short*)(ws + SZ_A + 3 * SZ_H);
  unsigned short* OUT1  = (unsigned short*)(ws + SZ_A + 4 * SZ_H);           // [64][2048] used
  unsigned short* WPACK = (unsigned short*)(ws + SZ_A + 4 * SZ_H + 262144);  // 57344 B
  unsigned short* WMB   = (unsigned short*)(ws + SZ_A + 4 * SZ_H + 319488);  // 32768 B
  unsigned short* WL    = (unsigned short*)(ws + SZ_A + 4 * SZ_H + 524288);  // 8 MB
  float*          YP    = (float*)(ws + SZ_A + 4 * SZ_H + 524288 + SZ_A);    // 8x[64][2048] f32

  wpack_kernel<<<112, 256, 0, stream>>>(w_st, WPACK);
  wmpack_kernel<<<64, 256, 0, stream>>>(w_mlp, WMB);
  adj_kernel<<<512, 256, 0, stream>>>(nv1, nv2, Ab);
  conv_kernel<<<dim3(32, BATCH), 256, 0, stream>>>(x, WPACK, b_st, H0);
  wlin_cvt<<<2048, 256, 0, stream>>>(w_lin, WL);

  gemm256<<<dim3(16, 16), 512, 0, stream>>>(H0, Ab, H0, H1);
  gemm256<<<dim3(16, 16), 512, 0, stream>>>(H1, Ab, H0, H2);
  gemm256<<<dim3(16, 16), 512, 0, stream>>>(H2, Ab, H0, H3);

  mlp_kernel<<<dim3(32, BATCH), 256, 0, stream>>>(H0, H1, H2, H3, WMB, b_mlp,
                                                  w_end, b_end, OUT1);
  gemm_tail<<<dim3(16, 8), 256, 0, stream>>>(OUT1, WL, YP);
  ln_kernel<<<BATCH, 256, 0, stream>>>(YP, b_lin, ln_g, ln_b, (float*)d_out);
}

// Round 12
// 271.183 us; speedup vs baseline: 1.1308x; 1.1308x over previous
//
#include <hip/hip_runtime.h>

#define NODE_NUM 2000
#define DM 2048          // D_MODEL, also padded K/N
#define IN_DIM 7
#define CONV_CH 64
#define KER 49
#define BATCH 64

typedef __attribute__((ext_vector_type(8))) short bf16x8;
typedef __attribute__((ext_vector_type(4))) float f32x4;
typedef __attribute__((ext_vector_type(4))) unsigned int u32x4;

__device__ __forceinline__ float bf2f(unsigned short u) {
  union { unsigned int i; float f; } c; c.i = ((unsigned int)u) << 16; return c.f;
}
__device__ __forceinline__ unsigned short f2bf(float f) {
  union { float f; unsigned int i; } c; c.f = f;
  unsigned int r = c.i + 0x7FFFu + ((c.i >> 16) & 1u);
  return (unsigned short)(r >> 16);
}

// ---------------------------------------------------------------------------
// Adjacency (round-9 verified): 4 rows/block, 8 consecutive w per thread.
// ---------------------------------------------------------------------------
__global__ __launch_bounds__(256) void adj_kernel(const float* __restrict__ nv1,
                                                  const float* __restrict__ nv2,
                                                  unsigned short* __restrict__ Ab) {
  const int bid = blockIdx.x;
  const int tid = threadIdx.x;
  if (bid >= 500) {
    const int r0 = 2000 + (bid - 500) * 4;
    for (int i = tid; i < 4 * 2048; i += 256)
      Ab[(size_t)(r0 + (i >> 11)) * DM + (i & 2047)] = 0;
    return;
  }
  const int v0 = bid * 4;
  __shared__ float e1s[4][40];
  __shared__ float redm[4][4], redsum[4][4];
  for (int i = tid; i < 160; i += 256) e1s[i / 40][i % 40] = nv1[(v0 + i / 40) * 40 + i % 40];
  __syncthreads();
  const int w0 = tid * 8;
  const bool oob = (w0 >= NODE_NUM);
  const float* base = nv2 + (oob ? 0 : w0);
  float acc[4][8] = {};
  f32x4 xa = *(const f32x4*)(base);
  f32x4 xb = *(const f32x4*)(base + 4);
  for (int k = 0; k < 40; ++k) {
    const f32x4 ca = xa, cb = xb;
    if (k < 39) {
      xa = *(const f32x4*)(base + (k + 1) * NODE_NUM);
      xb = *(const f32x4*)(base + (k + 1) * NODE_NUM + 4);
    }
#pragma unroll
    for (int v = 0; v < 4; ++v) {
      const float e = e1s[v][k];
#pragma unroll
      for (int i = 0; i < 4; ++i) {
        acc[v][i]     = fmaf(e, ca[i], acc[v][i]);
        acc[v][i + 4] = fmaf(e, cb[i], acc[v][i + 4]);
      }
    }
  }
  const int wid = tid >> 6, lane = tid & 63;
#pragma unroll
  for (int v = 0; v < 4; ++v) {
    float mx = -1e30f;
    if (!oob) {
#pragma unroll
      for (int i = 0; i < 8; ++i) {
        acc[v][i] = fmaxf(acc[v][i], 0.f);
        mx = fmaxf(mx, acc[v][i]);
      }
    }
    for (int o = 32; o; o >>= 1) mx = fmaxf(mx, __shfl_xor(mx, o));
    if (lane == 0) redm[v][wid] = mx;
  }
  __syncthreads();
#pragma unroll
  for (int v = 0; v < 4; ++v) {
    const float mx = fmaxf(fmaxf(redm[v][0], redm[v][1]), fmaxf(redm[v][2], redm[v][3]));
    float sum = 0.f;
    if (!oob) {
#pragma unroll
      for (int i = 0; i < 8; ++i) { const float e = __expf(acc[v][i] - mx); acc[v][i] = e; sum += e; }
    }
    for (int o = 32; o; o >>= 1) sum += __shfl_xor(sum, o);
    if (lane == 0) redsum[v][wid] = sum;
  }
  __syncthreads();
#pragma unroll
  for (int v = 0; v < 4; ++v) {
    const float sum = redsum[v][0] + redsum[v][1] + redsum[v][2] + redsum[v][3];
    const float inv = 0.5f / sum;
    const int vg = v0 + v;
    unsigned short out[8];
#pragma unroll
    for (int i = 0; i < 8; ++i) {
      const float val = oob ? 0.f : (acc[v][i] * inv + ((w0 + i == vg) ? 0.5f : 0.f));
      out[i] = f2bf(val);
    }
    *(u32x4*)(Ab + (size_t)vg * DM + w0) = *(const u32x4*)out;
  }
}

// ---------------------------------------------------------------------------
// Pack conv weights into per-lane MFMA A-fragment order (bf16).
// ---------------------------------------------------------------------------
__global__ __launch_bounds__(256) void wpack_kernel(const float* __restrict__ wst,
                                                    unsigned short* __restrict__ wpack) {
  const int idx = blockIdx.x * 256 + threadIdx.x;   // 112 blocks
  const int e = idx & 7;
  const int lane = (idx >> 3) & 63;
  const int w = (idx >> 9) & 3;
  const int kstep = idx >> 11;
  const int c = w * 16 + (lane & 15);
  const int k = kstep * 32 + (lane >> 4) * 8 + e;
  const int ci = k >> 6, kern = k & 63;
  const float val = (kern < KER) ? wst[(c * IN_DIM + ci) * KER + kern] : 0.f;
  wpack[idx] = f2bf(val);
}

// ---------------------------------------------------------------------------
// Pack MLP weights to bf16 once.
// ---------------------------------------------------------------------------
__global__ __launch_bounds__(256) void wmpack_kernel(const float* __restrict__ wm,
                                                     unsigned short* __restrict__ wmb) {
  const int idx = blockIdx.x * 256 + threadIdx.x;   // 64 blocks = 16384
  wmb[idx] = f2bf(wm[idx]);
}

// ---------------------------------------------------------------------------
// Start conv via MFMA with shift-replicated x copies (round-7 verified).
// ---------------------------------------------------------------------------
__global__ __launch_bounds__(256) void conv_kernel(const float* __restrict__ x,
                                                   const unsigned short* __restrict__ wpack,
                                                   const float* __restrict__ bst,
                                                   unsigned short* __restrict__ H0) {
  __shared__ alignas(16) unsigned short xcopy[8 * 7 * 128];  // 14336 B
  const int b = blockIdx.y;
  const int n0 = blockIdx.x * 64;
  const int tid = threadIdx.x;
  const int wv = tid >> 6, lane = tid & 63;
  const int l15 = lane & 15, kg = lane >> 4;
  bf16x8 af[14];
#pragma unroll
  for (int ks = 0; ks < 14; ++ks)
    af[ks] = *(const bf16x8*)(wpack + ((size_t)(ks * 4 + wv) * 64 + lane) * 8);
  f32x4 acc[4];
  {
    const f32x4 bv = *(const f32x4*)(bst + wv * 16 + kg * 4);
#pragma unroll
    for (int nf = 0; nf < 4; ++nf) acc[nf] = bv;
  }
  const size_t xb = (size_t)b * (IN_DIM * DM);
#pragma unroll
  for (int it = 0; it < 14; ++it) {
    const int row = it * 4 + (tid >> 6);       // 0..55
    const int s = row / 7, ci = row % 7;
    const int j = (tid & 63) * 2;
    int g0 = n0 + j + s;     if (g0 > DM - 1) g0 = DM - 1;
    int g1 = n0 + j + 1 + s; if (g1 > DM - 1) g1 = DM - 1;
    const float v0 = x[xb + ci * DM + g0];
    const float v1 = x[xb + ci * DM + g1];
    const unsigned int pk = (unsigned int)f2bf(v0) | ((unsigned int)f2bf(v1) << 16);
    *(unsigned int*)((char*)xcopy + row * 256 + j * 2) = pk;
  }
  __syncthreads();
#pragma unroll
  for (int ks = 0; ks < 14; ++ks) {
    const int ci = ks >> 1;
    const int kern0 = ((ks & 1) << 5) + kg * 8;
#pragma unroll
    for (int nf = 0; nf < 4; ++nf) {
      const int q = nf * 16 + l15 + kern0;
      const int byte = ((q & 7) * 7 + ci) * 256 + (q & ~7) * 2;
      const bf16x8 bfr = *(const bf16x8*)((const char*)xcopy + byte);
      acc[nf] = __builtin_amdgcn_mfma_f32_16x16x32_bf16(af[ks], bfr, acc[nf], 0, 0, 0);
    }
  }
#pragma unroll
  for (int nf = 0; nf < 4; ++nf) {
#pragma unroll
    for (int r = 0; r < 4; ++r) {
      const int c = wv * 16 + kg * 4 + r;
      const int n = n0 + nf * 16 + l15;
      H0[(size_t)(b * 64 + c) * DM + n] =
          (n < NODE_NUM) ? f2bf(acc[nf][r]) : (unsigned short)0;
    }
  }
}

// ---------------------------------------------------------------------------
// NT-GEMM: C[m][n] = sum_k A[m][k] * Bt[n][k], lda=ldb=ldc=2048.
// Depth-2 counted-vmcnt pipeline (round-10 verified) with compiler-scheduled
// ds_read/MFMA interleave: no manual lgkmcnt pin; MFMA before the
// __syncthreads(); STAGE(t+2) after it (overwrite-safe, ~2-iter load cover).
// MODE 0: full K, mixprop epilogue  out = bf16(0.05*H0 + 0.95*acc)
// MODE 1: split-K (blockIdx.y = split of 256 k's), m0=0, f32 partial out
// ---------------------------------------------------------------------------
template <int MODE>
__global__ __launch_bounds__(256) void gemm_nt(const unsigned short* __restrict__ A,
                                               const unsigned short* __restrict__ Bt,
                                               const unsigned short* __restrict__ H0,
                                               void* __restrict__ Cout) {
  __shared__ alignas(16) unsigned short As[2][128 * 64];
  __shared__ alignas(16) unsigned short Bs[2][128 * 64];
  const int tid = threadIdx.x;
  int bx, by;
  if (MODE == 0) {
    // T1: nwg=512, 512%8==0 -> each XCD gets 64 contiguous logical tiles
    const int lin = blockIdx.y * 16 + blockIdx.x;
    const int swz = (lin & 7) * 64 + (lin >> 3);
    bx = swz & 15;  by = swz >> 4;
  } else {
    bx = blockIdx.x;  by = blockIdx.y;
  }
  const int n0 = bx * 128;
  const int m0 = (MODE == 0) ? by * 128 : 0;
  const int kbeg = (MODE == 0) ? 0 : by * 256;
  const int nt = (MODE == 0) ? (DM / 64) : 4;   // always >= 2
  const int wid = tid >> 6, lane = tid & 63;
  const int wr = wid >> 1, wc = wid & 1;
  const int l15 = lane & 15, kg = lane >> 4;

  auto STAGE = [&](int buf, int k0) {
#pragma unroll
    for (int it = 0; it < 4; ++it) {
      const int lin = it * 4096 + tid * 16;
      const int row = lin >> 7;
      const int blog = (lin & 127) ^ ((row & 7) << 4);   // inverse swizzle -> logical
      const char* sa = (const char*)A + ((size_t)(m0 + row) * DM + k0) * 2 + blog;
      const char* sb = (const char*)Bt + ((size_t)(n0 + row) * DM + k0) * 2 + blog;
      __builtin_amdgcn_global_load_lds((const __attribute__((address_space(1))) void*)sa,
                                       (__attribute__((address_space(3))) void*)((char*)As[buf] + lin),
                                       16, 0, 0);
      __builtin_amdgcn_global_load_lds((const __attribute__((address_space(1))) void*)sb,
                                       (__attribute__((address_space(3))) void*)((char*)Bs[buf] + lin),
                                       16, 0, 0);
    }
  };

  f32x4 acc[4][4] = {};
  STAGE(0, kbeg);
  STAGE(1, kbeg + 64);

  for (int t = 0; t < nt; ++t) {
    const int cur = t & 1;
    if (t + 1 < nt) asm volatile("s_waitcnt vmcnt(8)" ::: "memory");
    else            asm volatile("s_waitcnt vmcnt(0)" ::: "memory");
    __builtin_amdgcn_s_barrier();            // tile t resident in buf[cur]
    __builtin_amdgcn_sched_barrier(0);       // keep ds_reads below the barrier
    bf16x8 af[2][4], bfr[2][4];
#pragma unroll
    for (int f = 0; f < 4; ++f) {
      const int ra = wr * 64 + f * 16 + l15;
      const int rb = wc * 64 + f * 16 + l15;
#pragma unroll
      for (int kk = 0; kk < 2; ++kk) {
        const int off = kk * 64 + kg * 16;
        af[kk][f]  = *(const bf16x8*)((const char*)As[cur] + ra * 128 + (off ^ ((ra & 7) << 4)));
        bfr[kk][f] = *(const bf16x8*)((const char*)Bs[cur] + rb * 128 + (off ^ ((rb & 7) << 4)));
      }
    }
    // no manual lgkmcnt pin: compiler interleaves reads and MFMAs with
    // fine-grained counted lgkmcnt waits.
#pragma unroll
    for (int kk = 0; kk < 2; ++kk)
#pragma unroll
      for (int mf = 0; mf < 4; ++mf)
#pragma unroll
        for (int nf = 0; nf < 4; ++nf)
          acc[mf][nf] = __builtin_amdgcn_mfma_f32_16x16x32_bf16(af[kk][mf], bfr[kk][nf],
                                                                acc[mf][nf], 0, 0, 0);
    __syncthreads();                          // all waves done reading buf[cur]
    if (t + 2 < nt) STAGE(cur, kbeg + (t + 2) * 64);
  }
  const int l4 = lane >> 4;
#pragma unroll
  for (int mf = 0; mf < 4; ++mf) {
#pragma unroll
    for (int nf = 0; nf < 4; ++nf) {
#pragma unroll
      for (int r = 0; r < 4; ++r) {
        const int gm = m0 + wr * 64 + mf * 16 + l4 * 4 + r;
        const int gn = n0 + wc * 64 + nf * 16 + l15;
        if (MODE == 0) {
          const float v = 0.05f * bf2f(H0[(size_t)gm * DM + gn]) + 0.95f * acc[mf][nf][r];
          ((unsigned short*)Cout)[(size_t)gm * DM + gn] = f2bf(v);
        } else {
          if (gm < 64)
            ((float*)Cout)[(size_t)blockIdx.y * 64 * DM + (size_t)gm * DM + gn] = acc[mf][nf][r];
        }
      }
    }
  }
}

// ---------------------------------------------------------------------------
// MLP via MFMA (verified structure, pre-packed bf16 weights).
// ---------------------------------------------------------------------------
__global__ __launch_bounds__(256) void mlp_kernel(const unsigned short* __restrict__ h0,
                                                  const unsigned short* __restrict__ h1,
                                                  const unsigned short* __restrict__ h2,
                                                  const unsigned short* __restrict__ h3,
                                                  const unsigned short* __restrict__ wmb,
                                                  const float* __restrict__ bm,
                                                  const float* __restrict__ we,
                                                  const float* __restrict__ be,
                                                  unsigned short* __restrict__ out1) {
  __shared__ alignas(16) unsigned short hs[64 * 264];
  __shared__ alignas(16) unsigned short wl[64 * 264];
  __shared__ float cbuf[128];
  const int b = blockIdx.y;
  const int gn0 = blockIdx.x * 64;
  const int tid = threadIdx.x;
#pragma unroll
  for (int it = 0; it < 8; ++it) {
    const int idx = it * 256 + tid;
    const int o = idx >> 5, c = (idx & 31) * 8;
    *(bf16x8*)&wl[o * 264 + c] = *(const bf16x8*)(wmb + o * 256 + c);
  }
  if (tid < 64) cbuf[tid] = bm[tid];
  else if (tid < 128) cbuf[tid] = we[tid - 64];
  char* hsb = (char*)hs;
#pragma unroll
  for (int it = 0; it < 8; ++it) {
    const int idx = it * 256 + tid;
    const int cf = idx >> 3, n0 = (idx & 7) * 8;
    const int hop = cf >> 6, c = cf & 63;
    const unsigned short* hb = (hop == 0) ? h0 : (hop == 1) ? h1 : (hop == 2) ? h2 : h3;
    const unsigned long long* p =
        (const unsigned long long*)(hb + (size_t)(b * 64 + c) * DM + gn0 + n0);
    const unsigned long long lo = p[0], hi = p[1];
#pragma unroll
    for (int t = 0; t < 8; ++t) {
      const int i = (t + tid) & 7;
      const unsigned short val = (unsigned short)(((i & 4) ? hi : lo) >> ((i & 3) * 16));
      *(unsigned short*)(hsb + (n0 + i) * 528 + cf * 2) = val;
    }
  }
  __syncthreads();
  const int wid = tid >> 6, lane = tid & 63;
  const int l15 = lane & 15, kg = lane >> 4;
  const char* wb = (const char*)wl;
  f32x4 acc[4] = {};
#pragma unroll
  for (int kk = 0; kk < 8; ++kk) {
    const int koff = kk * 64 + kg * 16;
    const bf16x8 bfr = *(const bf16x8*)(hsb + (wid * 16 + l15) * 528 + koff);
#pragma unroll
    for (int mf = 0; mf < 4; ++mf) {
      const bf16x8 af = *(const bf16x8*)(wb + (mf * 16 + l15) * 528 + koff);
      acc[mf] = __builtin_amdgcn_mfma_f32_16x16x32_bf16(af, bfr, acc[mf], 0, 0, 0);
    }
  }
  float pl = 0.f;
#pragma unroll
  for (int mf = 0; mf < 4; ++mf) {
#pragma unroll
    for (int r = 0; r < 4; ++r) {
      const int o = mf * 16 + kg * 4 + r;
      const float s = acc[mf][r] + cbuf[o];
      const float g = 0.5f * s * (1.f + erff(s * 0.70710678118f));
      pl += cbuf[64 + o] * g;
    }
  }
  pl += __shfl_xor(pl, 16);
  pl += __shfl_xor(pl, 32);
  if (kg == 0) {
    const int n = gn0 + wid * 16 + l15;
    out1[(size_t)b * DM + n] = (n < NODE_NUM) ? f2bf(pl + be[0]) : (unsigned short)0;
  }
}

// ---------------------------------------------------------------------------
// w_lin (2048 x 2000 f32) -> bf16 [2048][2048], pad cols zeroed (vectorized)
// ---------------------------------------------------------------------------
__global__ __launch_bounds__(256) void wlin_cvt(const float* __restrict__ wlin,
                                                unsigned short* __restrict__ wl) {
  const int idx = (blockIdx.x * 256 + threadIdx.x) * 8;   // 2048 blocks
  const int d = idx >> 11, w0 = idx & 2047;
  unsigned short out[8];
#pragma unroll
  for (int j = 0; j < 8; ++j) {
    const int w = w0 + j;
    out[j] = (w < NODE_NUM) ? f2bf(wlin[d * NODE_NUM + w]) : (unsigned short)0;
  }
  *(u32x4*)(wl + idx) = *(const u32x4*)out;
}

// ---------------------------------------------------------------------------
// sum 8 split-K partials, +b_lin, LayerNorm over 2048, f32 out
// ---------------------------------------------------------------------------
__global__ __launch_bounds__(256) void ln_kernel(const float* __restrict__ yp,
                                                 const float* __restrict__ bl,
                                                 const float* __restrict__ g,
                                                 const float* __restrict__ bb,
                                                 float* __restrict__ out) {
  const int b = blockIdx.x, tid = threadIdx.x;
  __shared__ float rs[4], rq[4];
  float v[8];
  float s = 0.f;
#pragma unroll
  for (int i = 0; i < 8; ++i) {
    const int d = i * 256 + tid;
    float acc = bl[d];
#pragma unroll
    for (int sp = 0; sp < 8; ++sp) acc += yp[(size_t)sp * 64 * DM + (size_t)b * DM + d];
    v[i] = acc;
    s += acc;
  }
  for (int o = 32; o; o >>= 1) s += __shfl_xor(s, o);
  const int wid = tid >> 6, lane = tid & 63;
  if (lane == 0) rs[wid] = s;
  __syncthreads();
  s = rs[0] + rs[1] + rs[2] + rs[3];
  const float mu = s * (1.f / 2048.f);
  float q = 0.f;
#pragma unroll
  for (int i = 0; i < 8; ++i) { const float d = v[i] - mu; q += d * d; }
  for (int o = 32; o; o >>= 1) q += __shfl_xor(q, o);
  if (lane == 0) rq[wid] = q;
  __syncthreads();
  q = rq[0] + rq[1] + rq[2] + rq[3];
  const float inv = rsqrtf(q * (1.f / 2048.f) + 1e-5f);
#pragma unroll
  for (int i = 0; i < 8; ++i) {
    const int d = i * 256 + tid;
    out[(size_t)b * DM + d] = (v[i] - mu) * inv * g[d] + bb[d];
  }
}

// ---------------------------------------------------------------------------
extern "C" void kernel_launch(void* const* d_in, const int* in_sizes, int n_in,
                              void* d_out, int out_size, void* d_ws, size_t ws_size,
                              hipStream_t stream) {
  const float* x      = (const float*)d_in[0];
  const float* nv1    = (const float*)d_in[1];
  const float* nv2    = (const float*)d_in[2];
  const float* w_st   = (const float*)d_in[3];
  const float* b_st   = (const float*)d_in[4];
  const float* w_mlp  = (const float*)d_in[5];
  const float* b_mlp  = (const float*)d_in[6];
  const float* w_end  = (const float*)d_in[7];
  const float* b_end  = (const float*)d_in[8];
  const float* w_lin  = (const float*)d_in[9];
  const float* b_lin  = (const float*)d_in[10];
  const float* ln_g   = (const float*)d_in[11];
  const float* ln_b   = (const float*)d_in[12];

  char* ws = (char*)d_ws;
  const size_t SZ_A = (size_t)DM * DM * 2;    // 8 MB
  const size_t SZ_H = (size_t)4096 * DM * 2;  // 16 MB
  unsigned short* Ab    = (unsigned short*)(ws);
  unsigned short* H0    = (unsigned short*)(ws + SZ_A);
  unsigned short* H1    = (unsigned short*)(ws + SZ_A + SZ_H);
  unsigned short* H2    = (unsigned short*)(ws + SZ_A + 2 * SZ_H);
  unsigned short* H3    = (unsigned short*)(ws + SZ_A + 3 * SZ_H);
  unsigned short* OUT1  = (unsigned short*)(ws + SZ_A + 4 * SZ_H);           // [64][2048] used
  unsigned short* WPACK = (unsigned short*)(ws + SZ_A + 4 * SZ_H + 262144);  // 57344 B
  unsigned short* WMB   = (unsigned short*)(ws + SZ_A + 4 * SZ_H + 319488);  // 32768 B
  unsigned short* WL    = (unsigned short*)(ws + SZ_A + 4 * SZ_H + 524288);  // 8 MB
  float*          YP    = (float*)(ws + SZ_A + 4 * SZ_H + 524288 + SZ_A);    // 8x[64][2048] f32

  wpack_kernel<<<112, 256, 0, stream>>>(w_st, WPACK);
  wmpack_kernel<<<64, 256, 0, stream>>>(w_mlp, WMB);
  adj_kernel<<<512, 256, 0, stream>>>(nv1, nv2, Ab);
  conv_kernel<<<dim3(32, BATCH), 256, 0, stream>>>(x, WPACK, b_st, H0);
  wlin_cvt<<<2048, 256, 0, stream>>>(w_lin, WL);

  gemm_nt<0><<<dim3(16, 32), 256, 0, stream>>>(H0, Ab, H0, (void*)H1);
  gemm_nt<0><<<dim3(16, 32), 256, 0, stream>>>(H1, Ab, H0, (void*)H2);
  gemm_nt<0><<<dim3(16, 32), 256, 0, stream>>>(H2, Ab, H0, (void*)H3);

  mlp_kernel<<<dim3(32, BATCH), 256, 0, stream>>>(H0, H1, H2, H3, WMB, b_mlp,
                                                  w_end, b_end, OUT1);
  gemm_nt<1><<<dim3(16, 8), 256, 0, stream>>>(OUT1, WL, (const unsigned short*)0, (void*)YP);
  ln_kernel<<<BATCH, 256, 0, stream>>>(YP, b_lin, ln_g, ln_b, (float*)d_out);
}